// Round 1
// baseline (516.073 us; speedup 1.0000x reference)
//
#include <hip/hip_runtime.h>
#include <math.h>

#define N_NODES 50000
#define N_EDGES 1600000
#define IN_DIM 128
#define N_HEADS 8
#define OUT_DIM 16
#define HD 128          // N_HEADS * OUT_DIM
#define NBLK 196        // ceil(N_NODES / 256)

// ---------------- W transpose: W[c][k] -> Wt[k][c] (64 KB, one-time) ----------------
__global__ void k_transpose_w(const float* __restrict__ W, float* __restrict__ Wt) {
    int flat4 = blockIdx.x * blockDim.x + threadIdx.x;   // over 4096 float4s
    if (flat4 >= (HD * IN_DIM) / 4) return;
    int c  = flat4 >> 5;   // 32 float4 per row of 128
    int k4 = flat4 & 31;
    float4 v = ((const float4*)W)[flat4];
    int k = k4 * 4;
    Wt[(k + 0) * HD + c] = v.x;
    Wt[(k + 1) * HD + c] = v.y;
    Wt[(k + 2) * HD + c] = v.z;
    Wt[(k + 3) * HD + c] = v.w;
}

// ---------------- projection: ft = x @ W^T, a1 = ft.attn_l, a2 = ft.attn_r ----------
// 32 nodes/block, 256 threads, each thread computes 4 nodes x 4 cols.
__global__ __launch_bounds__(256) void k_project(
    const float* __restrict__ x, const float* __restrict__ Wt,
    const float* __restrict__ attn_l, const float* __restrict__ attn_r,
    float* __restrict__ ft, float* __restrict__ a1, float* __restrict__ a2) {
    __shared__ float red_l[32][32];   // [node][h*4 + quarter]
    __shared__ float red_r[32][32];

    int tid = threadIdx.x;
    int cb = (tid & 31) * 4;       // column base (0..124)
    int nb = (tid >> 5) * 4;       // node base within block (0..28)
    int node0 = blockIdx.x * 32;

    float4 acc[4];
    acc[0] = acc[1] = acc[2] = acc[3] = make_float4(0.f, 0.f, 0.f, 0.f);

    const float* xrow[4];
#pragma unroll
    for (int i = 0; i < 4; i++) {
        int n = node0 + nb + i;
        if (n >= N_NODES) n = N_NODES - 1;   // clamp; stores are guarded
        xrow[i] = x + (size_t)n * IN_DIM;
    }

    for (int k = 0; k < IN_DIM; k += 4) {
        float4 w0 = *(const float4*)(Wt + (k + 0) * HD + cb);
        float4 w1 = *(const float4*)(Wt + (k + 1) * HD + cb);
        float4 w2 = *(const float4*)(Wt + (k + 2) * HD + cb);
        float4 w3 = *(const float4*)(Wt + (k + 3) * HD + cb);
#pragma unroll
        for (int i = 0; i < 4; i++) {
            float4 xv = *(const float4*)(xrow[i] + k);
            acc[i].x = fmaf(xv.w, w3.x, fmaf(xv.z, w2.x, fmaf(xv.y, w1.x, fmaf(xv.x, w0.x, acc[i].x))));
            acc[i].y = fmaf(xv.w, w3.y, fmaf(xv.z, w2.y, fmaf(xv.y, w1.y, fmaf(xv.x, w0.y, acc[i].y))));
            acc[i].z = fmaf(xv.w, w3.z, fmaf(xv.z, w2.z, fmaf(xv.y, w1.z, fmaf(xv.x, w0.z, acc[i].z))));
            acc[i].w = fmaf(xv.w, w3.w, fmaf(xv.z, w2.w, fmaf(xv.y, w1.w, fmaf(xv.x, w0.w, acc[i].w))));
        }
    }

    // store ft
#pragma unroll
    for (int i = 0; i < 4; i++) {
        int n = node0 + nb + i;
        if (n < N_NODES) *(float4*)(ft + (size_t)n * HD + cb) = acc[i];
    }

    // partial head dots for a1/a2
    int h   = cb >> 4;           // head
    int sub = cb & 15;           // offset within head (0,4,8,12)
    float4 al = *(const float4*)(attn_l + h * OUT_DIM + sub);
    float4 ar = *(const float4*)(attn_r + h * OUT_DIM + sub);
    int col = (h << 2) | (sub >> 2);
#pragma unroll
    for (int i = 0; i < 4; i++) {
        float pl = acc[i].x * al.x + acc[i].y * al.y + acc[i].z * al.z + acc[i].w * al.w;
        float pr = acc[i].x * ar.x + acc[i].y * ar.y + acc[i].z * ar.z + acc[i].w * ar.w;
        red_l[nb + i][col] = pl;
        red_r[nb + i][col] = pr;
    }
    __syncthreads();
    // 256 threads == 32 nodes x 8 heads
    int nl = tid >> 3, hh = tid & 7;
    int n = node0 + nl;
    if (n < N_NODES) {
        float s1 = red_l[nl][hh * 4 + 0] + red_l[nl][hh * 4 + 1] + red_l[nl][hh * 4 + 2] + red_l[nl][hh * 4 + 3];
        float s2 = red_r[nl][hh * 4 + 0] + red_r[nl][hh * 4 + 1] + red_r[nl][hh * 4 + 2] + red_r[nl][hh * 4 + 3];
        a1[n * N_HEADS + hh] = s1;
        a2[n * N_HEADS + hh] = s2;
    }
}

// ---------------- CSR build ----------------
__global__ void k_zero_deg(int* __restrict__ deg) {
    int i = blockIdx.x * 256 + threadIdx.x;
    if (i < N_NODES) deg[i] = 0;
}

__global__ void k_hist(const int* __restrict__ dst, int* __restrict__ deg) {
    int e = blockIdx.x * 256 + threadIdx.x;
    if (e < N_EDGES) atomicAdd(&deg[dst[e]], 1);
}

__global__ void k_blocksum(const int* __restrict__ deg, int* __restrict__ psum) {
    __shared__ int s[256];
    int i = blockIdx.x * 256 + threadIdx.x;
    s[threadIdx.x] = (i < N_NODES) ? deg[i] : 0;
    __syncthreads();
    for (int d = 128; d > 0; d >>= 1) {
        if (threadIdx.x < d) s[threadIdx.x] += s[threadIdx.x + d];
        __syncthreads();
    }
    if (threadIdx.x == 0) psum[blockIdx.x] = s[0];
}

__global__ void k_scan_psum(int* __restrict__ psum) {
    __shared__ int s[256];
    int t = threadIdx.x;
    s[t] = (t < NBLK) ? psum[t] : 0;
    __syncthreads();
    for (int d = 1; d < 256; d <<= 1) {
        int v = (t >= d) ? s[t - d] : 0;
        __syncthreads();
        s[t] += v;
        __syncthreads();
    }
    if (t < NBLK) psum[t] = (t == 0) ? 0 : s[t - 1];   // exclusive block bases
}

__global__ void k_offsets(const int* __restrict__ deg, const int* __restrict__ psum,
                          int* __restrict__ offs, int* __restrict__ cursor) {
    __shared__ int s[256];
    int t = threadIdx.x;
    int i = blockIdx.x * 256 + t;
    int d = (i < N_NODES) ? deg[i] : 0;
    s[t] = d;
    __syncthreads();
    for (int dd = 1; dd < 256; dd <<= 1) {
        int v = (t >= dd) ? s[t - dd] : 0;
        __syncthreads();
        s[t] += v;
        __syncthreads();
    }
    int excl = s[t] - d + psum[blockIdx.x];
    if (i < N_NODES) {
        offs[i] = excl;
        cursor[i] = excl;
        if (i == N_NODES - 1) offs[N_NODES] = excl + d;
    }
}

__global__ void k_scatter(const int* __restrict__ src, const int* __restrict__ dst,
                          int* __restrict__ cursor, int* __restrict__ esrc) {
    int e = blockIdx.x * 256 + threadIdx.x;
    if (e < N_EDGES) {
        int d = dst[e];
        int pos = atomicAdd(&cursor[d], 1);
        esrc[pos] = src[e];
    }
}

// ---------------- aggregation: one wave per dst node ----------------
__global__ __launch_bounds__(256) void k_aggregate(
    const float* __restrict__ ft, const float* __restrict__ a1, const float* __restrict__ a2,
    const int* __restrict__ offs, const int* __restrict__ esrc, float* __restrict__ out) {
    int node = blockIdx.x * 4 + (threadIdx.x >> 6);
    int lane = threadIdx.x & 63;
    int off = offs[node];
    int deg = offs[node + 1] - off;

    // phase A mapping: 8 edges x 8 heads per iteration
    int h1 = lane & 7;
    int es = lane >> 3;
    float a2h = a2[node * N_HEADS + h1];

    // pass 1: max
    float m = -INFINITY;
    for (int base = 0; base < deg; base += 8) {
        int e = base + es;
        if (e < deg) {
            int s = esrc[off + e];
            float t = a1[s * N_HEADS + h1] + a2h;
            t = t > 0.f ? t : 0.2f * t;
            m = fmaxf(m, t);
        }
    }
    m = fmaxf(m, __shfl_xor(m, 8));
    m = fmaxf(m, __shfl_xor(m, 16));
    m = fmaxf(m, __shfl_xor(m, 32));

    // pass 2: sum of exp
    float l = 0.f;
    for (int base = 0; base < deg; base += 8) {
        int e = base + es;
        if (e < deg) {
            int s = esrc[off + e];
            float t = a1[s * N_HEADS + h1] + a2h;
            t = t > 0.f ? t : 0.2f * t;
            l += __expf(t - m);
        }
    }
    l += __shfl_xor(l, 8);
    l += __shfl_xor(l, 16);
    l += __shfl_xor(l, 32);

    // phase B mapping: lane covers output dims {2*lane, 2*lane+1}, head = lane>>3
    int hl = lane >> 3;
    float m2   = __shfl(m, hl);
    float l2   = __shfl(l, hl);
    float a2h2 = __shfl(a2h, hl);
    float invl = (deg > 0) ? 1.f / l2 : 0.f;

    float accx = 0.f, accy = 0.f;
    for (int base = 0; base < deg; base += 64) {
        int idx = base + lane;
        int se = (idx < deg) ? esrc[off + idx] : 0;
        int nrem = min(64, deg - base);
        for (int j = 0; j < nrem; j++) {
            int s = __shfl(se, j);
            float t = a1[s * N_HEADS + hl] + a2h2;
            t = t > 0.f ? t : 0.2f * t;
            float w = __expf(t - m2) * invl;
            float2 f = *(const float2*)(ft + (size_t)s * HD + lane * 2);
            accx = fmaf(w, f.x, accx);
            accy = fmaf(w, f.y, accy);
        }
    }
    float2 o; o.x = accx; o.y = accy;
    *(float2*)(out + (size_t)node * HD + lane * 2) = o;
}

// ---------------- host launcher ----------------
extern "C" void kernel_launch(void* const* d_in, const int* in_sizes, int n_in,
                              void* d_out, int out_size, void* d_ws, size_t ws_size,
                              hipStream_t stream) {
    const float* x      = (const float*)d_in[0];
    const float* W      = (const float*)d_in[1];
    const float* attn_l = (const float*)d_in[2];
    const float* attn_r = (const float*)d_in[3];
    const int*   src    = (const int*)d_in[4];
    const int*   dst    = (const int*)d_in[5];
    float* out = (float*)d_out;

    char* ws = (char*)d_ws;
    size_t o = 0;
    auto alloc = [&](size_t bytes) -> char* {
        char* p = ws + o;
        o = (o + bytes + 255) & ~(size_t)255;
        return p;
    };
    float* ft     = (float*)alloc((size_t)N_NODES * HD * 4);       // 25.6 MB
    float* a1     = (float*)alloc((size_t)N_NODES * N_HEADS * 4);  // 1.6 MB
    float* a2     = (float*)alloc((size_t)N_NODES * N_HEADS * 4);  // 1.6 MB
    float* Wt     = (float*)alloc((size_t)HD * IN_DIM * 4);        // 64 KB
    int*   deg    = (int*)alloc((size_t)N_NODES * 4);
    int*   offs   = (int*)alloc((size_t)(N_NODES + 1) * 4);
    int*   cursor = (int*)alloc((size_t)N_NODES * 4);
    int*   psum   = (int*)alloc((size_t)NBLK * 4);
    int*   esrc   = (int*)alloc((size_t)N_EDGES * 4);              // 6.4 MB

    (void)in_sizes; (void)n_in; (void)out_size; (void)ws_size;

    k_transpose_w<<<16, 256, 0, stream>>>(W, Wt);
    k_project<<<(N_NODES + 31) / 32, 256, 0, stream>>>(x, Wt, attn_l, attn_r, ft, a1, a2);
    k_zero_deg<<<NBLK, 256, 0, stream>>>(deg);
    k_hist<<<(N_EDGES + 255) / 256, 256, 0, stream>>>(dst, deg);
    k_blocksum<<<NBLK, 256, 0, stream>>>(deg, psum);
    k_scan_psum<<<1, 256, 0, stream>>>(psum);
    k_offsets<<<NBLK, 256, 0, stream>>>(deg, psum, offs, cursor);
    k_scatter<<<(N_EDGES + 255) / 256, 256, 0, stream>>>(src, dst, cursor, esrc);
    k_aggregate<<<N_NODES / 4, 256, 0, stream>>>(ft, a1, a2, offs, esrc, out);
}

// Round 2
// 412.063 us; speedup vs baseline: 1.2524x; 1.2524x over previous
//
#include <hip/hip_runtime.h>
#include <math.h>

#define N_NODES 50000
#define N_EDGES 1600000
#define IN_DIM 128
#define N_HEADS 8
#define OUT_DIM 16
#define HD 128          // N_HEADS * OUT_DIM
#define NBLK 196        // ceil(N_NODES / 256)
#define DEG_CAP 128     // LDS-cached edges per node (fallback path beyond)

__device__ __forceinline__ unsigned short f2bf(float f) {
    union { float f; unsigned int u; } v; v.f = f;
    unsigned int u = v.u;
    unsigned int r = (u + 0x7fffu + ((u >> 16) & 1u)) >> 16;   // RN-even
    return (unsigned short)r;
}

// ---------------- W transpose: W[c][k] -> Wt[k][c] (64 KB, one-time) ----------------
__global__ void k_transpose_w(const float* __restrict__ W, float* __restrict__ Wt) {
    int flat4 = blockIdx.x * blockDim.x + threadIdx.x;   // over 4096 float4s
    if (flat4 >= (HD * IN_DIM) / 4) return;
    int c  = flat4 >> 5;   // 32 float4 per row of 128
    int k4 = flat4 & 31;
    float4 v = ((const float4*)W)[flat4];
    int k = k4 * 4;
    Wt[(k + 0) * HD + c] = v.x;
    Wt[(k + 1) * HD + c] = v.y;
    Wt[(k + 2) * HD + c] = v.z;
    Wt[(k + 3) * HD + c] = v.w;
}

// ---------------- projection: ft(bf16) = x @ W^T, a1 = ft.attn_l, a2 = ft.attn_r ----
// 32 nodes/block, 256 threads, each thread computes 4 nodes x 4 cols.
__global__ __launch_bounds__(256) void k_project(
    const float* __restrict__ x, const float* __restrict__ Wt,
    const float* __restrict__ attn_l, const float* __restrict__ attn_r,
    unsigned short* __restrict__ ftb, float* __restrict__ a1, float* __restrict__ a2) {
    __shared__ float red_l[32][32];   // [node][h*4 + quarter]
    __shared__ float red_r[32][32];

    int tid = threadIdx.x;
    int cb = (tid & 31) * 4;       // column base (0..124)
    int nb = (tid >> 5) * 4;       // node base within block (0..28)
    int node0 = blockIdx.x * 32;

    float4 acc[4];
    acc[0] = acc[1] = acc[2] = acc[3] = make_float4(0.f, 0.f, 0.f, 0.f);

    const float* xrow[4];
#pragma unroll
    for (int i = 0; i < 4; i++) {
        int n = node0 + nb + i;
        if (n >= N_NODES) n = N_NODES - 1;   // clamp; stores are guarded
        xrow[i] = x + (size_t)n * IN_DIM;
    }

    for (int k = 0; k < IN_DIM; k += 4) {
        float4 w0 = *(const float4*)(Wt + (k + 0) * HD + cb);
        float4 w1 = *(const float4*)(Wt + (k + 1) * HD + cb);
        float4 w2 = *(const float4*)(Wt + (k + 2) * HD + cb);
        float4 w3 = *(const float4*)(Wt + (k + 3) * HD + cb);
#pragma unroll
        for (int i = 0; i < 4; i++) {
            float4 xv = *(const float4*)(xrow[i] + k);
            acc[i].x = fmaf(xv.w, w3.x, fmaf(xv.z, w2.x, fmaf(xv.y, w1.x, fmaf(xv.x, w0.x, acc[i].x))));
            acc[i].y = fmaf(xv.w, w3.y, fmaf(xv.z, w2.y, fmaf(xv.y, w1.y, fmaf(xv.x, w0.y, acc[i].y))));
            acc[i].z = fmaf(xv.w, w3.z, fmaf(xv.z, w2.z, fmaf(xv.y, w1.z, fmaf(xv.x, w0.z, acc[i].z))));
            acc[i].w = fmaf(xv.w, w3.w, fmaf(xv.z, w2.w, fmaf(xv.y, w1.w, fmaf(xv.x, w0.w, acc[i].w))));
        }
    }

    // store ft as bf16 (halves the aggregate gather traffic)
#pragma unroll
    for (int i = 0; i < 4; i++) {
        int n = node0 + nb + i;
        if (n < N_NODES) {
            ushort4 us;
            us.x = f2bf(acc[i].x); us.y = f2bf(acc[i].y);
            us.z = f2bf(acc[i].z); us.w = f2bf(acc[i].w);
            *(ushort4*)(ftb + (size_t)n * HD + cb) = us;
        }
    }

    // partial head dots for a1/a2 (f32 exact from acc)
    int h   = cb >> 4;           // head
    int sub = cb & 15;           // offset within head (0,4,8,12)
    float4 al = *(const float4*)(attn_l + h * OUT_DIM + sub);
    float4 ar = *(const float4*)(attn_r + h * OUT_DIM + sub);
    int col = (h << 2) | (sub >> 2);
#pragma unroll
    for (int i = 0; i < 4; i++) {
        float pl = acc[i].x * al.x + acc[i].y * al.y + acc[i].z * al.z + acc[i].w * al.w;
        float pr = acc[i].x * ar.x + acc[i].y * ar.y + acc[i].z * ar.z + acc[i].w * ar.w;
        red_l[nb + i][col] = pl;
        red_r[nb + i][col] = pr;
    }
    __syncthreads();
    int nl = tid >> 3, hh = tid & 7;
    int n = node0 + nl;
    if (n < N_NODES) {
        float s1 = red_l[nl][hh * 4 + 0] + red_l[nl][hh * 4 + 1] + red_l[nl][hh * 4 + 2] + red_l[nl][hh * 4 + 3];
        float s2 = red_r[nl][hh * 4 + 0] + red_r[nl][hh * 4 + 1] + red_r[nl][hh * 4 + 2] + red_r[nl][hh * 4 + 3];
        a1[n * N_HEADS + hh] = s1;
        a2[n * N_HEADS + hh] = s2;
    }
}

// ---------------- CSR build ----------------
__global__ void k_zero_deg(int* __restrict__ deg) {
    int i = blockIdx.x * 256 + threadIdx.x;
    if (i < N_NODES) deg[i] = 0;
}

__global__ void k_hist(const int* __restrict__ dst, int* __restrict__ deg) {
    int e = blockIdx.x * 256 + threadIdx.x;
    if (e < N_EDGES) atomicAdd(&deg[dst[e]], 1);
}

__global__ void k_blocksum(const int* __restrict__ deg, int* __restrict__ psum) {
    __shared__ int s[256];
    int i = blockIdx.x * 256 + threadIdx.x;
    s[threadIdx.x] = (i < N_NODES) ? deg[i] : 0;
    __syncthreads();
    for (int d = 128; d > 0; d >>= 1) {
        if (threadIdx.x < d) s[threadIdx.x] += s[threadIdx.x + d];
        __syncthreads();
    }
    if (threadIdx.x == 0) psum[blockIdx.x] = s[0];
}

__global__ void k_scan_psum(int* __restrict__ psum) {
    __shared__ int s[256];
    int t = threadIdx.x;
    s[t] = (t < NBLK) ? psum[t] : 0;
    __syncthreads();
    for (int d = 1; d < 256; d <<= 1) {
        int v = (t >= d) ? s[t - d] : 0;
        __syncthreads();
        s[t] += v;
        __syncthreads();
    }
    if (t < NBLK) psum[t] = (t == 0) ? 0 : s[t - 1];   // exclusive block bases
}

__global__ void k_offsets(const int* __restrict__ deg, const int* __restrict__ psum,
                          int* __restrict__ offs, int* __restrict__ cursor) {
    __shared__ int s[256];
    int t = threadIdx.x;
    int i = blockIdx.x * 256 + t;
    int d = (i < N_NODES) ? deg[i] : 0;
    s[t] = d;
    __syncthreads();
    for (int dd = 1; dd < 256; dd <<= 1) {
        int v = (t >= dd) ? s[t - dd] : 0;
        __syncthreads();
        s[t] += v;
        __syncthreads();
    }
    int excl = s[t] - d + psum[blockIdx.x];
    if (i < N_NODES) {
        offs[i] = excl;
        cursor[i] = excl;
        if (i == N_NODES - 1) offs[N_NODES] = excl + d;
    }
}

__global__ void k_scatter(const int* __restrict__ src, const int* __restrict__ dst,
                          int* __restrict__ cursor, int* __restrict__ esrc) {
    int e = blockIdx.x * 256 + threadIdx.x;
    if (e < N_EDGES) {
        int d = dst[e];
        int pos = atomicAdd(&cursor[d], 1);
        esrc[pos] = src[e];
    }
}

// ---------------- aggregation: one wave per dst node, LDS-cached weights ----------
// No max-subtraction: logits are bounded (|t| <~ 30), exp() cannot overflow f32;
// result is mathematically identical to the reference's stabilized softmax.
__global__ __launch_bounds__(256) void k_aggregate(
    const unsigned short* __restrict__ ftb, const float* __restrict__ a1,
    const float* __restrict__ a2, const int* __restrict__ offs,
    const int* __restrict__ esrc, float* __restrict__ out) {
    __shared__ float lw[4][DEG_CAP * N_HEADS];   // normalized weights
    __shared__ int   ls[4][DEG_CAP];             // src indices

    int wid  = threadIdx.x >> 6;
    int lane = threadIdx.x & 63;
    int node = blockIdx.x * 4 + wid;
    float* w  = lw[wid];
    int*   si = ls[wid];

    int off = offs[node];
    int deg = offs[node + 1] - off;

    // phase A: 8 edges x 8 heads per iteration; accumulate denom, cache exp in LDS
    int h1 = lane & 7;
    int es = lane >> 3;
    float a2h = a2[node * N_HEADS + h1];

    float l = 0.f;
    for (int base = 0; base < deg; base += 8) {
        int e = base + es;
        if (e < deg) {
            int s = esrc[off + e];
            float t = a1[s * N_HEADS + h1] + a2h;
            t = t > 0.f ? t : 0.2f * t;
            float ww = __expf(t);
            l += ww;
            if (e < DEG_CAP) {
                w[e * N_HEADS + h1] = ww;
                if (h1 == 0) si[e] = s;
            }
        }
    }
    l += __shfl_xor(l, 8);
    l += __shfl_xor(l, 16);
    l += __shfl_xor(l, 32);
    float invl = (deg > 0) ? 1.f / l : 0.f;   // per-head (keyed by h1)

    // normalize cached weights in LDS (per-wave private; no barrier needed)
    int lim = min(deg, DEG_CAP);
    for (int e = es; e < lim; e += 8) w[e * N_HEADS + h1] *= invl;

    // phase B: lane covers dims {2*lane, 2*lane+1}, head = lane>>3
    int hl = lane >> 3;
    float invl2 = __shfl(invl, hl);
    float a2h2  = __shfl(a2h, hl);

    float accx = 0.f, accy = 0.f;
#pragma unroll 4
    for (int j = 0; j < lim; j++) {
        float ww = w[j * N_HEADS + hl];
        int s = si[j];
        unsigned int p = *(const unsigned int*)(ftb + (size_t)s * HD + lane * 2);
        float fx = __uint_as_float(p << 16);
        float fy = __uint_as_float(p & 0xffff0000u);
        accx = fmaf(ww, fx, accx);
        accy = fmaf(ww, fy, accy);
    }
    // fallback for deg > DEG_CAP (statistically never for Poisson(32), kept for correctness)
    for (int j = DEG_CAP; j < deg; j++) {
        int s = esrc[off + j];
        float t = a1[s * N_HEADS + hl] + a2h2;
        t = t > 0.f ? t : 0.2f * t;
        float ww = __expf(t) * invl2;
        unsigned int p = *(const unsigned int*)(ftb + (size_t)s * HD + lane * 2);
        accx = fmaf(ww, __uint_as_float(p << 16), accx);
        accy = fmaf(ww, __uint_as_float(p & 0xffff0000u), accy);
    }

    float2 o; o.x = accx; o.y = accy;
    *(float2*)(out + (size_t)node * HD + lane * 2) = o;
}

// ---------------- host launcher ----------------
extern "C" void kernel_launch(void* const* d_in, const int* in_sizes, int n_in,
                              void* d_out, int out_size, void* d_ws, size_t ws_size,
                              hipStream_t stream) {
    const float* x      = (const float*)d_in[0];
    const float* W      = (const float*)d_in[1];
    const float* attn_l = (const float*)d_in[2];
    const float* attn_r = (const float*)d_in[3];
    const int*   src    = (const int*)d_in[4];
    const int*   dst    = (const int*)d_in[5];
    float* out = (float*)d_out;

    char* ws = (char*)d_ws;
    size_t o = 0;
    auto alloc = [&](size_t bytes) -> char* {
        char* p = ws + o;
        o = (o + bytes + 255) & ~(size_t)255;
        return p;
    };
    unsigned short* ftb = (unsigned short*)alloc((size_t)N_NODES * HD * 2);  // 12.8 MB bf16
    float* a1     = (float*)alloc((size_t)N_NODES * N_HEADS * 4);
    float* a2     = (float*)alloc((size_t)N_NODES * N_HEADS * 4);
    float* Wt     = (float*)alloc((size_t)HD * IN_DIM * 4);
    int*   deg    = (int*)alloc((size_t)N_NODES * 4);
    int*   offs   = (int*)alloc((size_t)(N_NODES + 1) * 4);
    int*   cursor = (int*)alloc((size_t)N_NODES * 4);
    int*   psum   = (int*)alloc((size_t)NBLK * 4);
    int*   esrc   = (int*)alloc((size_t)N_EDGES * 4);

    (void)in_sizes; (void)n_in; (void)out_size; (void)ws_size;

    k_transpose_w<<<16, 256, 0, stream>>>(W, Wt);
    k_project<<<(N_NODES + 31) / 32, 256, 0, stream>>>(x, Wt, attn_l, attn_r, ftb, a1, a2);
    k_zero_deg<<<NBLK, 256, 0, stream>>>(deg);
    k_hist<<<(N_EDGES + 255) / 256, 256, 0, stream>>>(dst, deg);
    k_blocksum<<<NBLK, 256, 0, stream>>>(deg, psum);
    k_scan_psum<<<1, 256, 0, stream>>>(psum);
    k_offsets<<<NBLK, 256, 0, stream>>>(deg, psum, offs, cursor);
    k_scatter<<<(N_EDGES + 255) / 256, 256, 0, stream>>>(src, dst, cursor, esrc);
    k_aggregate<<<N_NODES / 4, 256, 0, stream>>>(ftb, a1, a2, offs, esrc, out);
}

// Round 3
// 253.375 us; speedup vs baseline: 2.0368x; 1.6263x over previous
//
#include <hip/hip_runtime.h>
#include <math.h>

#define N_NODES 50000
#define N_EDGES 1600000
#define IN_DIM 128
#define N_HEADS 8
#define OUT_DIM 16
#define HD 128            // N_HEADS * OUT_DIM
#define DEG_CAP 128       // LDS-cached edges per node in aggregate
#define NBUCK 196         // ceil(N_NODES / 256) coarse buckets (256 nodes each)
#define BCAP 12288        // region capacity per bucket (avg ~8163, 45 sigma headroom)
#define CHUNK 4096        // edges per k_bin block
#define BIN_BLOCKS ((N_EDGES + CHUNK - 1) / CHUNK)   // 391

__device__ __forceinline__ unsigned short f2bf(float f) {
    union { float f; unsigned int u; } v; v.f = f;
    unsigned int u = v.u;
    unsigned int r = (u + 0x7fffu + ((u >> 16) & 1u)) >> 16;   // RN-even
    return (unsigned short)r;
}

// ---------------- W transpose + zero bin state (one-time, fused) ----------------
__global__ void k_transpose_w(const float* __restrict__ W, float* __restrict__ Wt,
                              int* __restrict__ bucket_cnt, int* __restrict__ ovf_cnt) {
    if (blockIdx.x == 0) {
        int t = threadIdx.x;
        if (t < NBUCK) bucket_cnt[t] = 0;
        if (t == 0) *ovf_cnt = 0;
    }
    int flat4 = blockIdx.x * blockDim.x + threadIdx.x;   // over 4096 float4s
    if (flat4 >= (HD * IN_DIM) / 4) return;
    int c  = flat4 >> 5;
    int k4 = flat4 & 31;
    float4 v = ((const float4*)W)[flat4];
    int k = k4 * 4;
    Wt[(k + 0) * HD + c] = v.x;
    Wt[(k + 1) * HD + c] = v.y;
    Wt[(k + 2) * HD + c] = v.z;
    Wt[(k + 3) * HD + c] = v.w;
}

// ---------------- projection: ft(bf16) = x @ W^T, a1/a2 head dots ----------------
__global__ __launch_bounds__(256) void k_project(
    const float* __restrict__ x, const float* __restrict__ Wt,
    const float* __restrict__ attn_l, const float* __restrict__ attn_r,
    unsigned short* __restrict__ ftb, float* __restrict__ a1, float* __restrict__ a2) {
    __shared__ float red_l[32][32];
    __shared__ float red_r[32][32];

    int tid = threadIdx.x;
    int cb = (tid & 31) * 4;
    int nb = (tid >> 5) * 4;
    int node0 = blockIdx.x * 32;

    float4 acc[4];
    acc[0] = acc[1] = acc[2] = acc[3] = make_float4(0.f, 0.f, 0.f, 0.f);

    const float* xrow[4];
#pragma unroll
    for (int i = 0; i < 4; i++) {
        int n = node0 + nb + i;
        if (n >= N_NODES) n = N_NODES - 1;
        xrow[i] = x + (size_t)n * IN_DIM;
    }

    for (int k = 0; k < IN_DIM; k += 4) {
        float4 w0 = *(const float4*)(Wt + (k + 0) * HD + cb);
        float4 w1 = *(const float4*)(Wt + (k + 1) * HD + cb);
        float4 w2 = *(const float4*)(Wt + (k + 2) * HD + cb);
        float4 w3 = *(const float4*)(Wt + (k + 3) * HD + cb);
#pragma unroll
        for (int i = 0; i < 4; i++) {
            float4 xv = *(const float4*)(xrow[i] + k);
            acc[i].x = fmaf(xv.w, w3.x, fmaf(xv.z, w2.x, fmaf(xv.y, w1.x, fmaf(xv.x, w0.x, acc[i].x))));
            acc[i].y = fmaf(xv.w, w3.y, fmaf(xv.z, w2.y, fmaf(xv.y, w1.y, fmaf(xv.x, w0.y, acc[i].y))));
            acc[i].z = fmaf(xv.w, w3.z, fmaf(xv.z, w2.z, fmaf(xv.y, w1.z, fmaf(xv.x, w0.z, acc[i].z))));
            acc[i].w = fmaf(xv.w, w3.w, fmaf(xv.z, w2.w, fmaf(xv.y, w1.w, fmaf(xv.x, w0.w, acc[i].w))));
        }
    }

#pragma unroll
    for (int i = 0; i < 4; i++) {
        int n = node0 + nb + i;
        if (n < N_NODES) {
            ushort4 us;
            us.x = f2bf(acc[i].x); us.y = f2bf(acc[i].y);
            us.z = f2bf(acc[i].z); us.w = f2bf(acc[i].w);
            *(ushort4*)(ftb + (size_t)n * HD + cb) = us;
        }
    }

    int h   = cb >> 4;
    int sub = cb & 15;
    float4 al = *(const float4*)(attn_l + h * OUT_DIM + sub);
    float4 ar = *(const float4*)(attn_r + h * OUT_DIM + sub);
    int col = (h << 2) | (sub >> 2);
#pragma unroll
    for (int i = 0; i < 4; i++) {
        float pl = acc[i].x * al.x + acc[i].y * al.y + acc[i].z * al.z + acc[i].w * al.w;
        float pr = acc[i].x * ar.x + acc[i].y * ar.y + acc[i].z * ar.z + acc[i].w * ar.w;
        red_l[nb + i][col] = pl;
        red_r[nb + i][col] = pr;
    }
    __syncthreads();
    int nl = tid >> 3, hh = tid & 7;
    int n = node0 + nl;
    if (n < N_NODES) {
        float s1 = red_l[nl][hh * 4 + 0] + red_l[nl][hh * 4 + 1] + red_l[nl][hh * 4 + 2] + red_l[nl][hh * 4 + 3];
        float s2 = red_r[nl][hh * 4 + 0] + red_r[nl][hh * 4 + 1] + red_r[nl][hh * 4 + 2] + red_r[nl][hh * 4 + 3];
        a1[n * N_HEADS + hh] = s1;
        a2[n * N_HEADS + hh] = s2;
    }
}

// ---------------- pass 1: bin edges into coarse buckets (contiguous runs) --------
// Edge packed into uint32: (dst << 16) | src  (both < 65536). bucket = pack >> 24.
__global__ __launch_bounds__(256) void k_bin(
    const int* __restrict__ src, const int* __restrict__ dst,
    unsigned int* __restrict__ region, int* __restrict__ bucket_cnt,
    int* __restrict__ ovf_cnt, unsigned int* __restrict__ ovf) {
    __shared__ unsigned int stage[CHUNK];        // 16 KB
    __shared__ int hist[256], scan[256], loff[256], lcur[256], rbase[256];
    int t = threadIdx.x;
    int base = blockIdx.x * CHUNK;
    int nvalid = min(CHUNK, N_EDGES - base);

    hist[t] = 0;
    __syncthreads();

    unsigned int mypack[CHUNK / 256];
#pragma unroll
    for (int k = 0; k < CHUNK / 256; k++) {
        int i = t + k * 256;
        if (i < nvalid) {
            int s = src[base + i];
            int d = dst[base + i];
            unsigned int p = ((unsigned int)d << 16) | (unsigned int)s;
            mypack[k] = p;
            atomicAdd(&hist[d >> 8], 1);
        }
    }
    __syncthreads();
    int h = hist[t];
    scan[t] = h;
    __syncthreads();
    for (int d2 = 1; d2 < 256; d2 <<= 1) {
        int u = (t >= d2) ? scan[t - d2] : 0;
        __syncthreads();
        scan[t] += u;
        __syncthreads();
    }
    int excl = scan[t] - h;
    loff[t] = excl;
    lcur[t] = excl;
    rbase[t] = (t < NBUCK && h > 0) ? atomicAdd(&bucket_cnt[t], h) : 0;
    __syncthreads();
#pragma unroll
    for (int k = 0; k < CHUNK / 256; k++) {
        int i = t + k * 256;
        if (i < nvalid) {
            unsigned int p = mypack[k];
            int slot = atomicAdd(&lcur[p >> 24], 1);
            stage[slot] = p;
        }
    }
    __syncthreads();
    for (int i = t; i < nvalid; i += 256) {
        unsigned int p = stage[i];
        int b = p >> 24;
        int pos = rbase[b] + (i - loff[b]);
        if (pos < BCAP) region[(size_t)b * BCAP + pos] = p;
        else { int o = atomicAdd(ovf_cnt, 1); ovf[o] = p; }
    }
}

// ---------------- tiny scan over 196 bucket counts ----------------
__global__ void k_bucket_scan(const int* __restrict__ bucket_cnt,
                              int* __restrict__ bucket_base, int* __restrict__ offs) {
    __shared__ int s[256];
    int t = threadIdx.x;
    int v = (t < NBUCK) ? bucket_cnt[t] : 0;
    s[t] = v;
    __syncthreads();
    for (int d = 1; d < 256; d <<= 1) {
        int u = (t >= d) ? s[t - d] : 0;
        __syncthreads();
        s[t] += u;
        __syncthreads();
    }
    if (t < NBUCK) bucket_base[t] = s[t] - v;
    if (t == 0) offs[N_NODES] = N_EDGES;
}

// ---------------- pass 2: per-bucket CSR offsets + placement ----------------
__global__ __launch_bounds__(256) void k_place(
    const unsigned int* __restrict__ region, const int* __restrict__ bucket_cnt,
    const int* __restrict__ bucket_base, const int* __restrict__ ovf_cnt,
    const unsigned int* __restrict__ ovf,
    int* __restrict__ offs, int* __restrict__ esrc) {
    int b = blockIdx.x;
    int t = threadIdx.x;
    __shared__ int hist[256], s[256], curs[256];
    hist[t] = 0;
    __syncthreads();

    int truec = bucket_cnt[b];
    int rc = min(truec, BCAP);
    const unsigned int* reg = region + (size_t)b * BCAP;
    for (int i = t; i < rc; i += 256) atomicAdd(&hist[(reg[i] >> 16) & 255], 1);
    int no = 0;
    if (truec > BCAP) {           // statistically never; correctness fallback
        no = *ovf_cnt;
        for (int i = t; i < no; i += 256)
            if ((int)(ovf[i] >> 24) == b) atomicAdd(&hist[(ovf[i] >> 16) & 255], 1);
    }
    __syncthreads();
    int h = hist[t];
    s[t] = h;
    __syncthreads();
    for (int d = 1; d < 256; d <<= 1) {
        int u = (t >= d) ? s[t - d] : 0;
        __syncthreads();
        s[t] += u;
        __syncthreads();
    }
    int pos0 = bucket_base[b] + s[t] - h;
    int node = b * 256 + t;
    if (node < N_NODES) offs[node] = pos0;
    curs[t] = pos0;
    __syncthreads();
    for (int i = t; i < rc; i += 256) {
        unsigned int p = reg[i];
        int pos = atomicAdd(&curs[(p >> 16) & 255], 1);
        esrc[pos] = (int)(p & 0xffffu);
    }
    if (truec > BCAP) {
        for (int i = t; i < no; i += 256) {
            unsigned int p = ovf[i];
            if ((int)(p >> 24) == b) {
                int pos = atomicAdd(&curs[(p >> 16) & 255], 1);
                esrc[pos] = (int)(p & 0xffffu);
            }
        }
    }
}

// ---------------- aggregation: one wave per dst node, LDS-cached weights ----------
__global__ __launch_bounds__(256) void k_aggregate(
    const unsigned short* __restrict__ ftb, const float* __restrict__ a1,
    const float* __restrict__ a2, const int* __restrict__ offs,
    const int* __restrict__ esrc, float* __restrict__ out) {
    __shared__ float lw[4][DEG_CAP * N_HEADS];
    __shared__ int   ls[4][DEG_CAP];

    int wid  = threadIdx.x >> 6;
    int lane = threadIdx.x & 63;
    int node = blockIdx.x * 4 + wid;
    float* w  = lw[wid];
    int*   si = ls[wid];

    int off = offs[node];
    int deg = offs[node + 1] - off;

    int h1 = lane & 7;
    int es = lane >> 3;
    float a2h = a2[node * N_HEADS + h1];

    float l = 0.f;
    for (int base = 0; base < deg; base += 8) {
        int e = base + es;
        if (e < deg) {
            int s = esrc[off + e];
            float t = a1[s * N_HEADS + h1] + a2h;
            t = t > 0.f ? t : 0.2f * t;
            float ww = __expf(t);
            l += ww;
            if (e < DEG_CAP) {
                w[e * N_HEADS + h1] = ww;
                if (h1 == 0) si[e] = s;
            }
        }
    }
    l += __shfl_xor(l, 8);
    l += __shfl_xor(l, 16);
    l += __shfl_xor(l, 32);
    float invl = (deg > 0) ? 1.f / l : 0.f;

    int lim = min(deg, DEG_CAP);
    for (int e = es; e < lim; e += 8) w[e * N_HEADS + h1] *= invl;

    int hl = lane >> 3;
    float invl2 = __shfl(invl, hl);
    float a2h2  = __shfl(a2h, hl);

    float accx = 0.f, accy = 0.f;
#pragma unroll 4
    for (int j = 0; j < lim; j++) {
        float ww = w[j * N_HEADS + hl];
        int s = si[j];
        unsigned int p = *(const unsigned int*)(ftb + (size_t)s * HD + lane * 2);
        float fx = __uint_as_float(p << 16);
        float fy = __uint_as_float(p & 0xffff0000u);
        accx = fmaf(ww, fx, accx);
        accy = fmaf(ww, fy, accy);
    }
    for (int j = DEG_CAP; j < deg; j++) {
        int s = esrc[off + j];
        float t = a1[s * N_HEADS + hl] + a2h2;
        t = t > 0.f ? t : 0.2f * t;
        float ww = __expf(t) * invl2;
        unsigned int p = *(const unsigned int*)(ftb + (size_t)s * HD + lane * 2);
        accx = fmaf(ww, __uint_as_float(p << 16), accx);
        accy = fmaf(ww, __uint_as_float(p & 0xffff0000u), accy);
    }

    float2 o; o.x = accx; o.y = accy;
    *(float2*)(out + (size_t)node * HD + lane * 2) = o;
}

// ---------------- host launcher ----------------
extern "C" void kernel_launch(void* const* d_in, const int* in_sizes, int n_in,
                              void* d_out, int out_size, void* d_ws, size_t ws_size,
                              hipStream_t stream) {
    const float* x      = (const float*)d_in[0];
    const float* W      = (const float*)d_in[1];
    const float* attn_l = (const float*)d_in[2];
    const float* attn_r = (const float*)d_in[3];
    const int*   src    = (const int*)d_in[4];
    const int*   dst    = (const int*)d_in[5];
    float* out = (float*)d_out;

    char* ws = (char*)d_ws;
    size_t o = 0;
    auto alloc = [&](size_t bytes) -> char* {
        char* p = ws + o;
        o = (o + bytes + 255) & ~(size_t)255;
        return p;
    };
    unsigned short* ftb = (unsigned short*)alloc((size_t)N_NODES * HD * 2);     // 12.8 MB
    float* a1          = (float*)alloc((size_t)N_NODES * N_HEADS * 4);          // 1.6 MB
    float* a2          = (float*)alloc((size_t)N_NODES * N_HEADS * 4);          // 1.6 MB
    float* Wt          = (float*)alloc((size_t)HD * IN_DIM * 4);                // 64 KB
    unsigned int* region = (unsigned int*)alloc((size_t)NBUCK * BCAP * 4);      // 9.6 MB
    int* bucket_cnt    = (int*)alloc((size_t)NBUCK * 4);
    int* bucket_base   = (int*)alloc((size_t)NBUCK * 4);
    int* ovf_cnt       = (int*)alloc(4);
    unsigned int* ovf  = (unsigned int*)alloc((size_t)N_EDGES * 4);             // 6.4 MB
    int* offs          = (int*)alloc((size_t)(N_NODES + 1) * 4);
    int* esrc          = (int*)alloc((size_t)N_EDGES * 4);                      // 6.4 MB

    (void)in_sizes; (void)n_in; (void)out_size; (void)ws_size;

    k_transpose_w<<<16, 256, 0, stream>>>(W, Wt, bucket_cnt, ovf_cnt);
    k_project<<<(N_NODES + 31) / 32, 256, 0, stream>>>(x, Wt, attn_l, attn_r, ftb, a1, a2);
    k_bin<<<BIN_BLOCKS, 256, 0, stream>>>(src, dst, region, bucket_cnt, ovf_cnt, ovf);
    k_bucket_scan<<<1, 256, 0, stream>>>(bucket_cnt, bucket_base, offs);
    k_place<<<NBUCK, 256, 0, stream>>>(region, bucket_cnt, bucket_base, ovf_cnt, ovf, offs, esrc);
    k_aggregate<<<N_NODES / 4, 256, 0, stream>>>(ftb, a1, a2, offs, esrc, out);
}